// Round 5
// baseline (468.073 us; speedup 1.0000x reference)
//
#include <hip/hip_runtime.h>
#include <cmath>

#define NB 8
#define NN 20000
#define ND 128
#define NE_TOT 192000   /* 3 edge sets * 64000 edges, contiguous per batch */
#define NPASS 5
#define NXCD 8
#define PCH 160         /* rows per pool block */
#define PBLK 125        /* NN / PCH, exact */

// Weight ping-pong, per-XCD atomic accumulator copies, pool partials, pooled.
__device__ float g_w0[NB * NN];
__device__ float g_w1[NB * NN];
__device__ float g_copy[NXCD][NB * NN];        // 5.12 MB total, 640 KB per XCD
__device__ float g_ppart[NB * PBLK * ND];      // 512 KB
__device__ float g_pooled[NB * ND];

__device__ __forceinline__ int xcc_id() {
    int x;
    asm volatile("s_getreg_b32 %0, hwreg(HW_REG_XCC_ID)" : "=s"(x));
    return x & (NXCD - 1);  // guard range; any value is CORRECT, locality is perf-only
}

__global__ void initK() {
    const size_t i = (size_t)blockIdx.x * blockDim.x + threadIdx.x;
    if (i < NB * NN) g_w0[i] = 1.0f;
    if (i < (size_t)NXCD * NB * NN) ((float*)g_copy)[i] = 0.0f;
}

// One thread per edge: copy[xcc][b][src] += w[b][dst].  All atomics to a given
// copy come from one XCD -> local L2 RMW, no cross-XCD line bouncing.
__global__ void scatterX(const int* __restrict__ edges, int src_sel) {
    const float* __restrict__ w = (src_sel == 0) ? g_w0 : g_w1;
    const int tid = blockIdx.x * blockDim.x + threadIdx.x;
    if (tid >= NB * NE_TOT) return;
    const int b = tid / NE_TOT;
    const int2 e = ((const int2*)edges)[tid];  // e.x = dst, e.y = src
    const int xcc = xcc_id();
    unsafeAtomicAdd(&g_copy[xcc][b * NN + e.y], w[b * NN + e.x]);
}

// w_next = w_cur + sum_x copy[x]; re-zero copies for the next pass.
__global__ void mergeZero(int src_sel) {
    const float4* __restrict__ w = (const float4*)((src_sel == 0) ? g_w0 : g_w1);
    float4* __restrict__ wn      = (float4*)((src_sel == 0) ? g_w1 : g_w0);
    const int i4 = blockIdx.x * blockDim.x + threadIdx.x;
    if (i4 >= NB * NN / 4) return;
    float4 v = w[i4];
    const float4 z = {0.f, 0.f, 0.f, 0.f};
    for (int x = 0; x < NXCD; ++x) {
        float4* cp = (float4*)g_copy[x];
        const float4 p = cp[i4];
        v.x += p.x; v.y += p.y; v.z += p.z; v.w += p.w;
        cp[i4] = z;
    }
    wn[i4] = v;
}

// pooled partials: block (bx, b) covers rows [bx*160, bx*160+160).
// Fully unrolled, 4 independent accumulator chains -> ~16 loads in flight.
__global__ void poolWK(const float* __restrict__ nodes, int wsel) {
    const float* __restrict__ w = (wsel == 0) ? g_w0 : g_w1;
    const int b  = blockIdx.y;
    const int r0 = blockIdx.x * PCH;
    const int t  = threadIdx.x;   // 256
    const int dslot = t & 31;     // float4 column
    const int rg    = t >> 5;     // row group 0..7
    const float4* __restrict__ base = (const float4*)(nodes + (size_t)b * NN * ND);
    const float* __restrict__ wb = w + b * NN;

    float4 a0 = {0,0,0,0}, a1 = {0,0,0,0}, a2 = {0,0,0,0}, a3 = {0,0,0,0};
#pragma unroll
    for (int k = 0; k < 5; ++k) {
        const int r = r0 + rg + k * 32;
        const float w0 = wb[r], w1 = wb[r + 8], w2 = wb[r + 16], w3 = wb[r + 24];
        const float4 v0 = base[(size_t)(r)      * 32 + dslot];
        const float4 v1 = base[(size_t)(r + 8)  * 32 + dslot];
        const float4 v2 = base[(size_t)(r + 16) * 32 + dslot];
        const float4 v3 = base[(size_t)(r + 24) * 32 + dslot];
        a0.x += w0 * v0.x; a0.y += w0 * v0.y; a0.z += w0 * v0.z; a0.w += w0 * v0.w;
        a1.x += w1 * v1.x; a1.y += w1 * v1.y; a1.z += w1 * v1.z; a1.w += w1 * v1.w;
        a2.x += w2 * v2.x; a2.y += w2 * v2.y; a2.z += w2 * v2.z; a2.w += w2 * v2.w;
        a3.x += w3 * v3.x; a3.y += w3 * v3.y; a3.z += w3 * v3.z; a3.w += w3 * v3.w;
    }
    float4 acc;
    acc.x = (a0.x + a1.x) + (a2.x + a3.x);
    acc.y = (a0.y + a1.y) + (a2.y + a3.y);
    acc.z = (a0.z + a1.z) + (a2.z + a3.z);
    acc.w = (a0.w + a1.w) + (a2.w + a3.w);

    __shared__ float4 red[256];
    red[t] = acc;
    __syncthreads();
    if (t < 32) {
        float4 s = red[t];
        for (int g = 1; g < 8; ++g) {
            const float4 o = red[g * 32 + t];
            s.x += o.x; s.y += o.y; s.z += o.z; s.w += o.w;
        }
        // per-block partial, no atomics
        ((float4*)g_ppart)[((size_t)b * PBLK + blockIdx.x) * 32 + t] = s;
    }
}

// g_pooled[b][d] = sum over 125 block-partials (coalesced across d)
__global__ void reduceK() {
    const int gid = blockIdx.x * blockDim.x + threadIdx.x;  // 0..1023
    if (gid >= NB * ND) return;
    const int b = gid >> 7, d = gid & 127;
    float s = 0.0f;
    for (int p = 0; p < PBLK; ++p)
        s += g_ppart[((size_t)b * PBLK + p) * ND + d];
    g_pooled[gid] = s;
}

// log / nan->0 / relu / inf->finite_max / concat / MLP head. Tiny; one block.
__global__ void headK(const float* __restrict__ ptype,
                      const float* __restrict__ w1, const float* __restrict__ b1,
                      const float* __restrict__ w2, const float* __restrict__ b2,
                      const float* __restrict__ w3, const float* __restrict__ b3,
                      float* __restrict__ out) {
    __shared__ float sx[NB][ND + 1];  // y (128) + problem_type (1)
    __shared__ float sh1[NB][80];
    __shared__ float sh2[NB][80];
    const int t = threadIdx.x;  // blockDim.x == 256

    for (int i = t; i < NB * ND; i += 256) {
        const int b = i >> 7, d = i & 127;
        float y = logf(g_pooled[i]);
        if (isnan(y)) y = 0.0f;        // nan -> 0
        y = fmaxf(y, 0.0f);            // relu (also folds -inf -> 0)
        sx[b][d] = y;
    }
    __syncthreads();

    if (t < NB) {
        float fm = -INFINITY;
        for (int d = 0; d < ND; ++d) {
            const float y = sx[t][d];
            if (!isinf(y)) fm = fmaxf(fm, y);
        }
        for (int d = 0; d < ND; ++d)
            if (isinf(sx[t][d])) sx[t][d] = fm;  // +inf -> finite_max
        sx[t][ND] = ptype[t];
    }
    __syncthreads();

    for (int i = t; i < NB * 80; i += 256) {
        const int b = i / 80, j = i - b * 80;
        float s = b1[j];
        for (int k = 0; k < ND + 1; ++k) s += sx[b][k] * w1[k * 80 + j];
        sh1[b][j] = s > 0.0f ? s : 0.01f * s;  // leaky_relu
    }
    __syncthreads();

    for (int i = t; i < NB * 80; i += 256) {
        const int b = i / 80, j = i - b * 80;
        float s = b2[j];
        for (int k = 0; k < 80; ++k) s += sh1[b][k] * w2[k * 80 + j];
        sh2[b][j] = s > 0.0f ? s : 0.01f * s;
    }
    __syncthreads();

    for (int i = t; i < NB * 10; i += 256) {
        const int b = i / 10, j = i - b * 10;
        float s = b3[j];
        for (int k = 0; k < 80; ++k) s += sh2[b][k] * w3[k * 10 + j];
        out[b * 10 + j] = s;
    }
}

extern "C" void kernel_launch(void* const* d_in, const int* in_sizes, int n_in,
                              void* d_out, int out_size, void* d_ws, size_t ws_size,
                              hipStream_t stream) {
    const float* nodes = (const float*)d_in[0];
    const float* ptype = (const float*)d_in[1];
    const float* w1    = (const float*)d_in[2];
    const float* b1    = (const float*)d_in[3];
    const float* w2    = (const float*)d_in[4];
    const float* b2    = (const float*)d_in[5];
    const float* w3    = (const float*)d_in[6];
    const float* b3    = (const float*)d_in[7];
    const int*   edges = (const int*)d_in[8];
    float* out = (float*)d_out;

    // zero copies + w0 = 1
    initK<<<(NXCD * NB * NN + 255) / 256, 256, 0, stream>>>();

    int sel = 0;  // current w lives in g_w0
    for (int p = 0; p < NPASS; ++p) {
        scatterX<<<NB * NE_TOT / 256, 256, 0, stream>>>(edges, sel);
        mergeZero<<<(NB * NN / 4 + 255) / 256, 256, 0, stream>>>(sel);
        sel ^= 1;  // current w is now the other buffer
    }

    poolWK<<<dim3(PBLK, NB), 256, 0, stream>>>(nodes, sel);
    reduceK<<<4, 256, 0, stream>>>();
    headK<<<1, 256, 0, stream>>>(ptype, w1, b1, w2, b2, w3, b3, out);
}

// Round 6
// 149.697 us; speedup vs baseline: 3.1268x; 3.1268x over previous
//
#include <hip/hip_runtime.h>
#include <cmath>

#define NB 8
#define NN 20000
#define ND 128
#define NE_TOT 192000   /* 3 edge sets * 64000 edges, contiguous per batch */
#define NPASS 5

#define RSZ 128                     /* nodes per src-range */
#define NR 157                      /* ceil(NN / RSZ) */
#define CAP 2048                    /* bucket capacity; avg fill 1229 (+23 sigma) */
#define ECHUNK 8000                 /* edges per bucketing block */
#define NCHUNK 24                   /* NE_TOT / ECHUNK, exact */

#define PCH 80                      /* rows per pool block */
#define PBLK 250                    /* NN / PCH, exact */

// ping-pong weight vectors + bucketing metadata + buckets + pool partials
__device__ float g_w0[NB * NN];
__device__ float g_w1[NB * NN];
__device__ int   g_bcnt[NB][NCHUNK][NR];
__device__ int   g_boff[NB][NCHUNK][NR];
__device__ int   g_cnt[NB * NR];
__device__ int2  g_bucket[(size_t)NB * NR * CAP];   // 20.6 MB
__device__ float g_ppart[(size_t)NB * PBLK * ND];   // 1 MB
__device__ float g_pooled[NB * ND];

__global__ void initK() {
    const int i = blockIdx.x * blockDim.x + threadIdx.x;
    if (i < NB * NN) g_w0[i] = 1.0f;
}

// ---- bucket build (once per call; edges are identical across the 5 passes) ----

__global__ void countK(const int* __restrict__ edges) {
    __shared__ int hist[NR];
    const int b = blockIdx.x / NCHUNK, c = blockIdx.x % NCHUNK;
    const int t = threadIdx.x;  // 256
    for (int i = t; i < NR; i += 256) hist[i] = 0;
    __syncthreads();
    const int2* __restrict__ ep =
        (const int2*)edges + (size_t)b * NE_TOT + (size_t)c * ECHUNK;
    for (int i = t; i < ECHUNK; i += 256)
        atomicAdd(&hist[ep[i].y >> 7], 1);
    __syncthreads();
    for (int i = t; i < NR; i += 256) g_bcnt[b][c][i] = hist[i];
}

__global__ void scanK() {  // per-(b,range): prefix counts over chunks
    const int b = blockIdx.x, t = threadIdx.x;
    if (t < NR) {
        int run = 0;
        for (int c = 0; c < NCHUNK; ++c) {
            g_boff[b][c][t] = run;
            run += g_bcnt[b][c][t];
        }
        g_cnt[b * NR + t] = run;
    }
}

__global__ void distK(const int* __restrict__ edges) {
    __shared__ int cur[NR];
    const int b = blockIdx.x / NCHUNK, c = blockIdx.x % NCHUNK;
    const int t = threadIdx.x;  // 256
    for (int i = t; i < NR; i += 256) cur[i] = g_boff[b][c][i];
    __syncthreads();
    const int2* __restrict__ ep =
        (const int2*)edges + (size_t)b * NE_TOT + (size_t)c * ECHUNK;
    for (int i = t; i < ECHUNK; i += 256) {
        const int2 e = ep[i];             // e.x = dst, e.y = src
        const int r = e.y >> 7;
        const int pos = atomicAdd(&cur[r], 1);
        if (pos < CAP)                    // impossible for uniform input; guards corruption
            g_bucket[((size_t)b * NR + r) * CAP + pos] = make_int2(e.x, e.y & (RSZ - 1));
    }
}

// ---- one propagation pass: w_next = w + A^T w, range-partitioned, no global atomics ----

__global__ void passK(int sel) {
    __shared__ float acc[RSZ];          // 512 B
    const int b = blockIdx.x / NR, r = blockIdx.x % NR;
    const int t = threadIdx.x;          // 256
    const float* __restrict__ w  = sel ? g_w1 : g_w0;
    float* __restrict__ wn       = sel ? g_w0 : g_w1;
    if (t < RSZ) acc[t] = 0.0f;
    __syncthreads();
    const int cnt = g_cnt[b * NR + r];
    const int2* __restrict__ bk = g_bucket + ((size_t)b * NR + r) * CAP;
    const float* __restrict__ wb = w + b * NN;
    for (int i = t; i < cnt; i += 256) {
        const int2 e = bk[i];           // e.x = dst (global), e.y = src (local)
        unsafeAtomicAdd(&acc[e.y], wb[e.x]);   // ds_add_f32
    }
    __syncthreads();
    const int node = (r << 7) + t;
    if (t < RSZ && node < NN)
        wn[b * NN + node] = wb[node] + acc[t];
}

// ---- pooled[b][d] = sum_n w[b][n] * nodes[b][n][d] (single streaming read) ----

__global__ void poolWK(const float* __restrict__ nodes, int wsel) {
    const float* __restrict__ w = wsel ? g_w1 : g_w0;
    const int b  = blockIdx.y;
    const int r0 = blockIdx.x * PCH;
    const int t  = threadIdx.x;   // 256
    const int dslot = t & 31;     // float4 column
    const int rg    = t >> 5;     // row group 0..7
    const float4* __restrict__ base = (const float4*)(nodes + (size_t)b * NN * ND);
    const float* __restrict__ wb = w + b * NN;

    float4 a[4];
    a[0] = a[1] = a[2] = a[3] = make_float4(0.f, 0.f, 0.f, 0.f);
#pragma unroll
    for (int k = 0; k < 10; ++k) {      // fully unrolled -> static a[k&3] indexing
        const int r = r0 + rg + k * 8;
        const float wv = wb[r];
        const float4 v = base[(size_t)r * 32 + dslot];
        a[k & 3].x += wv * v.x; a[k & 3].y += wv * v.y;
        a[k & 3].z += wv * v.z; a[k & 3].w += wv * v.w;
    }
    float4 acc;
    acc.x = (a[0].x + a[1].x) + (a[2].x + a[3].x);
    acc.y = (a[0].y + a[1].y) + (a[2].y + a[3].y);
    acc.z = (a[0].z + a[1].z) + (a[2].z + a[3].z);
    acc.w = (a[0].w + a[1].w) + (a[2].w + a[3].w);

    __shared__ float4 red[256];
    red[t] = acc;
    __syncthreads();
    if (t < 32) {
        float4 s = red[t];
        for (int g = 1; g < 8; ++g) {
            const float4 o = red[g * 32 + t];
            s.x += o.x; s.y += o.y; s.z += o.z; s.w += o.w;
        }
        ((float4*)g_ppart)[((size_t)b * PBLK + blockIdx.x) * 32 + t] = s;
    }
}

__global__ void reduceK() {  // grid NB blocks x 1024 threads
    const int b = blockIdx.x, t = threadIdx.x;
    const int d = t & 127, slice = t >> 7;   // 8 slices over the 250 partials
    float s = 0.0f;
    for (int p = slice; p < PBLK; p += 8)
        s += g_ppart[((size_t)b * PBLK + p) * ND + d];
    __shared__ float sh[1024];
    sh[t] = s;
    __syncthreads();
    if (t < 128) {
        float v = sh[t];
        for (int g = 1; g < 8; ++g) v += sh[g * 128 + t];
        g_pooled[b * ND + t] = v;
    }
}

// log / nan->0 / relu / inf->finite_max / concat / MLP head. Tiny; one block.
__global__ void headK(const float* __restrict__ ptype,
                      const float* __restrict__ w1, const float* __restrict__ b1,
                      const float* __restrict__ w2, const float* __restrict__ b2,
                      const float* __restrict__ w3, const float* __restrict__ b3,
                      float* __restrict__ out) {
    __shared__ float sx[NB][ND + 1];
    __shared__ float sh1[NB][80];
    __shared__ float sh2[NB][80];
    const int t = threadIdx.x;  // 256

    for (int i = t; i < NB * ND; i += 256) {
        const int b = i >> 7, d = i & 127;
        float y = logf(g_pooled[i]);
        if (isnan(y)) y = 0.0f;
        y = fmaxf(y, 0.0f);
        sx[b][d] = y;
    }
    __syncthreads();

    if (t < NB) {
        float fm = -INFINITY;
        for (int d = 0; d < ND; ++d) {
            const float y = sx[t][d];
            if (!isinf(y)) fm = fmaxf(fm, y);
        }
        for (int d = 0; d < ND; ++d)
            if (isinf(sx[t][d])) sx[t][d] = fm;
        sx[t][ND] = ptype[t];
    }
    __syncthreads();

    for (int i = t; i < NB * 80; i += 256) {
        const int b = i / 80, j = i - b * 80;
        float s = b1[j];
        for (int k = 0; k < ND + 1; ++k) s += sx[b][k] * w1[k * 80 + j];
        sh1[b][j] = s > 0.0f ? s : 0.01f * s;
    }
    __syncthreads();

    for (int i = t; i < NB * 80; i += 256) {
        const int b = i / 80, j = i - b * 80;
        float s = b2[j];
        for (int k = 0; k < 80; ++k) s += sh1[b][k] * w2[k * 80 + j];
        sh2[b][j] = s > 0.0f ? s : 0.01f * s;
    }
    __syncthreads();

    for (int i = t; i < NB * 10; i += 256) {
        const int b = i / 10, j = i - b * 10;
        float s = b3[j];
        for (int k = 0; k < 80; ++k) s += sh2[b][k] * w3[k * 10 + j];
        out[b * 10 + j] = s;
    }
}

extern "C" void kernel_launch(void* const* d_in, const int* in_sizes, int n_in,
                              void* d_out, int out_size, void* d_ws, size_t ws_size,
                              hipStream_t stream) {
    const float* nodes = (const float*)d_in[0];
    const float* ptype = (const float*)d_in[1];
    const float* w1    = (const float*)d_in[2];
    const float* b1    = (const float*)d_in[3];
    const float* w2    = (const float*)d_in[4];
    const float* b2    = (const float*)d_in[5];
    const float* w3    = (const float*)d_in[6];
    const float* b3    = (const float*)d_in[7];
    const int*   edges = (const int*)d_in[8];
    float* out = (float*)d_out;

    initK<<<(NB * NN + 255) / 256, 256, 0, stream>>>();

    // bucket build (amortized over the 5 passes)
    countK<<<NB * NCHUNK, 256, 0, stream>>>(edges);
    scanK<<<NB, 256, 0, stream>>>();
    distK<<<NB * NCHUNK, 256, 0, stream>>>(edges);

    int sel = 0;  // current w lives in g_w0
    for (int p = 0; p < NPASS; ++p) {
        passK<<<NB * NR, 256, 0, stream>>>(sel);
        sel ^= 1;
    }

    poolWK<<<dim3(PBLK, NB), 256, 0, stream>>>(nodes, sel);
    reduceK<<<NB, 1024, 0, stream>>>();
    headK<<<1, 256, 0, stream>>>(ptype, w1, b1, w2, b2, w3, b3, out);
}